// Round 1
// baseline (498.662 us; speedup 1.0000x reference)
//
#include <hip/hip_runtime.h>
#include <hip/hip_cooperative_groups.h>

namespace cg = cooperative_groups;

#define L_MAX 5
#define D_DIM 32
#define BLOCK 256
#define PPT   4   // pairs per thread in the fused kernel

// ---------------------------------------------------------------------------
// Fused no-workspace kernel (cooperative).
// Stages precomp[e*L+l] = dot(edge_vector[l], edge_attr[e]) in out[0..E*L),
// grid-syncs, computes all pair means into registers, grid-syncs, writes out.
// Never touches d_ws -> harness has no 256MiB workspace to re-poison.
// ---------------------------------------------------------------------------
__global__ __launch_bounds__(BLOCK, 4)
void fused_no_ws_kernel(const float* __restrict__ edge_attr,
                        const float* __restrict__ edge_vector,
                        const int* __restrict__ path_edges,
                        const int* __restrict__ path_len,
                        float* __restrict__ out,
                        int E, int P) {
    __shared__ float ev[L_MAX * D_DIM];
    const int tid = threadIdx.x;
    if (tid < L_MAX * D_DIM) ev[tid] = edge_vector[tid];
    __syncthreads();

    const int gtid = blockIdx.x * BLOCK + tid;
    const int nthreads = gridDim.x * BLOCK;

    // ---- Phase A: precompute per-edge per-hop dots into out[0 .. E*L) ----
    float* precomp = out;
    if (gtid < E) {
        const float4* row = (const float4*)(edge_attr + (size_t)gtid * D_DIM);
        float acc[L_MAX];
#pragma unroll
        for (int l = 0; l < L_MAX; ++l) acc[l] = 0.f;
#pragma unroll
        for (int c4 = 0; c4 < D_DIM / 4; ++c4) {
            float4 a = row[c4];
#pragma unroll
            for (int l = 0; l < L_MAX; ++l) {
                const float* evl = ev + l * D_DIM + c4 * 4;
                acc[l] += evl[0] * a.x + evl[1] * a.y + evl[2] * a.z + evl[3] * a.w;
            }
        }
#pragma unroll
        for (int l = 0; l < L_MAX; ++l)
            precomp[(size_t)gtid * L_MAX + l] = acc[l];
    }

    // release: drain stores + write back L2 so other XCDs can see precomp
    __threadfence();
    cg::this_grid().sync();
    // acquire: invalidate potentially-stale (poison-valued) L2 lines
    __threadfence();

    // ---- Phase B: masked path means, results held in registers ----
    float val[PPT];
#pragma unroll
    for (int i = 0; i < PPT; ++i) {
        const int p = gtid + i * nthreads;
        val[i] = 0.f;
        if (p < P) {
            const int len = path_len[p];
            const int* pe = path_edges + (size_t)p * L_MAX;
            const int e0 = pe[0], e1 = pe[1], e2 = pe[2], e3 = pe[3], e4 = pe[4];
            float s = 0.f;
            if (0 < len) s += precomp[(size_t)e0 * L_MAX + 0];
            if (1 < len) s += precomp[(size_t)e1 * L_MAX + 1];
            if (2 < len) s += precomp[(size_t)e2 * L_MAX + 2];
            if (3 < len) s += precomp[(size_t)e3 * L_MAX + 3];
            if (4 < len) s += precomp[(size_t)e4 * L_MAX + 4];
            val[i] = (len > 0) ? s / (float)len : 0.f;
        }
    }

    // forces vmcnt(0): all Phase-B gathers complete before anyone clobbers precomp
    __threadfence();
    cg::this_grid().sync();

    // ---- Phase C: write results (overwrites precomp region — safe now) ----
#pragma unroll
    for (int i = 0; i < PPT; ++i) {
        const int p = gtid + i * nthreads;
        if (p < P) out[p] = val[i];
    }
}

// ---------------------------------------------------------------------------
// Fallback path (previous best): two kernels through d_ws.
// ---------------------------------------------------------------------------
__global__ void precompute_dots_kernel(const float* __restrict__ edge_attr,
                                       const float* __restrict__ edge_vector,
                                       float* __restrict__ precomp, int E) {
    __shared__ float ev[L_MAX * D_DIM];
    int tid = threadIdx.x;
    if (tid < L_MAX * D_DIM) ev[tid] = edge_vector[tid];
    __syncthreads();

    int e = blockIdx.x * blockDim.x + tid;
    if (e >= E) return;

    const float4* row = (const float4*)(edge_attr + (size_t)e * D_DIM);
    float acc[L_MAX];
#pragma unroll
    for (int l = 0; l < L_MAX; ++l) acc[l] = 0.f;
#pragma unroll
    for (int c4 = 0; c4 < D_DIM / 4; ++c4) {
        float4 a = row[c4];
#pragma unroll
        for (int l = 0; l < L_MAX; ++l) {
            const float* evl = ev + l * D_DIM + c4 * 4;
            acc[l] += evl[0] * a.x + evl[1] * a.y + evl[2] * a.z + evl[3] * a.w;
        }
    }
#pragma unroll
    for (int l = 0; l < L_MAX; ++l)
        precomp[(size_t)e * L_MAX + l] = acc[l];
}

__global__ void path_mean_kernel(const int* __restrict__ path_edges,
                                 const int* __restrict__ path_len,
                                 const float* __restrict__ precomp,
                                 float* __restrict__ out, int P) {
    int p = blockIdx.x * blockDim.x + threadIdx.x;
    if (p >= P) return;

    int len = path_len[p];
    const int* pe = path_edges + (size_t)p * L_MAX;
    int e0 = pe[0], e1 = pe[1], e2 = pe[2], e3 = pe[3], e4 = pe[4];

    float s = 0.f;
    if (0 < len) s += precomp[(size_t)e0 * L_MAX + 0];
    if (1 < len) s += precomp[(size_t)e1 * L_MAX + 1];
    if (2 < len) s += precomp[(size_t)e2 * L_MAX + 2];
    if (3 < len) s += precomp[(size_t)e3 * L_MAX + 3];
    if (4 < len) s += precomp[(size_t)e4 * L_MAX + 4];

    out[p] = (len > 0) ? s / (float)len : 0.f;
}

__global__ void path_mean_direct_kernel(const int* __restrict__ path_edges,
                                        const int* __restrict__ path_len,
                                        const float* __restrict__ edge_attr,
                                        const float* __restrict__ edge_vector,
                                        float* __restrict__ out, int P) {
    __shared__ float ev[L_MAX * D_DIM];
    int tid = threadIdx.x;
    if (tid < L_MAX * D_DIM) ev[tid] = edge_vector[tid];
    __syncthreads();

    int p = blockIdx.x * blockDim.x + tid;
    if (p >= P) return;

    int len = path_len[p];
    const int* pe = path_edges + (size_t)p * L_MAX;

    float s = 0.f;
#pragma unroll
    for (int l = 0; l < L_MAX; ++l) {
        if (l < len) {
            const float4* row = (const float4*)(edge_attr + (size_t)pe[l] * D_DIM);
            float d = 0.f;
#pragma unroll
            for (int c4 = 0; c4 < D_DIM / 4; ++c4) {
                float4 a = row[c4];
                const float* evl = ev + l * D_DIM + c4 * 4;
                d += evl[0] * a.x + evl[1] * a.y + evl[2] * a.z + evl[3] * a.w;
            }
            s += d;
        }
    }
    out[p] = (len > 0) ? s / (float)len : 0.f;
}

extern "C" void kernel_launch(void* const* d_in, const int* in_sizes, int n_in,
                              void* d_out, int out_size, void* d_ws, size_t ws_size,
                              hipStream_t stream) {
    // Inputs (setup_inputs order): x [N*D], edge_attr [E*D], edge_vector [L*D],
    // path_edges [P*L] int32, path_len [P] int32. x is UNUSED by the reference.
    const float* edge_attr   = (const float*)d_in[1];
    const float* edge_vector = (const float*)d_in[2];
    const int*   path_edges  = (const int*)d_in[3];
    const int*   path_len    = (const int*)d_in[4];
    float* out = (float*)d_out;

    const int E = in_sizes[1] / D_DIM;
    const int P = in_sizes[4];

    // ---- Preferred: fused cooperative kernel, zero workspace usage ----
    const int fused_grid = (P + BLOCK * PPT - 1) / (BLOCK * PPT);
    const bool can_fuse =
        ((size_t)E * L_MAX <= (size_t)P) &&            // precomp fits inside out
        (fused_grid <= 1024) &&                        // co-resident @ 4 blocks/CU
        ((size_t)fused_grid * BLOCK >= (size_t)E);     // Phase A covers every edge

    if (can_fuse) {
        void* args[] = { (void*)&edge_attr, (void*)&edge_vector, (void*)&path_edges,
                         (void*)&path_len, (void*)&out, (void*)&E, (void*)&P };
        hipError_t err = hipLaunchCooperativeKernel(
            reinterpret_cast<void*>(fused_no_ws_kernel),
            dim3(fused_grid), dim3(BLOCK), args, 0, stream);
        if (err == hipSuccess) return;
        // fall through to workspace path on failure
    }

    const size_t precomp_bytes = (size_t)E * L_MAX * sizeof(float);
    if (ws_size >= precomp_bytes) {
        float* precomp = (float*)d_ws;
        {
            int block = 256;
            int grid = (E + block - 1) / block;
            precompute_dots_kernel<<<grid, block, 0, stream>>>(edge_attr, edge_vector,
                                                               precomp, E);
        }
        {
            int block = 256;
            int grid = (P + block - 1) / block;
            path_mean_kernel<<<grid, block, 0, stream>>>(path_edges, path_len,
                                                         precomp, out, P);
        }
    } else {
        int block = 256;
        int grid = (P + block - 1) / block;
        path_mean_direct_kernel<<<grid, block, 0, stream>>>(path_edges, path_len,
                                                            edge_attr, edge_vector,
                                                            out, P);
    }
}

// Round 2
// 107.163 us; speedup vs baseline: 4.6533x; 4.6533x over previous
//
#include <hip/hip_runtime.h>

#define L_MAX 5
#define D_DIM 32

typedef float f32x4 __attribute__((ext_vector_type(4)));

// Kernel 1: precomp[e*L + l] = dot(edge_vector[l], edge_attr[e])
// E threads, each reads one 128B row via float4 and produces 5 scalars.
// edge_attr is streamed once -> non-temporal loads (don't pollute L2;
// precomp writes SHOULD stay in L2 for kernel 2's gathers).
__global__ __launch_bounds__(256)
void precompute_dots_kernel(const float* __restrict__ edge_attr,
                            const float* __restrict__ edge_vector,
                            float* __restrict__ precomp, int E) {
    __shared__ float ev[L_MAX * D_DIM];
    int tid = threadIdx.x;
    if (tid < L_MAX * D_DIM) ev[tid] = edge_vector[tid];
    __syncthreads();

    int e = blockIdx.x * blockDim.x + tid;
    if (e >= E) return;

    const f32x4* row = (const f32x4*)(edge_attr + (size_t)e * D_DIM);
    float acc[L_MAX];
#pragma unroll
    for (int l = 0; l < L_MAX; ++l) acc[l] = 0.f;

#pragma unroll
    for (int c4 = 0; c4 < D_DIM / 4; ++c4) {
        f32x4 a = __builtin_nontemporal_load(row + c4);
#pragma unroll
        for (int l = 0; l < L_MAX; ++l) {
            const float* evl = ev + l * D_DIM + c4 * 4;
            acc[l] += evl[0] * a.x + evl[1] * a.y + evl[2] * a.z + evl[3] * a.w;
        }
    }
#pragma unroll
    for (int l = 0; l < L_MAX; ++l)
        precomp[(size_t)e * L_MAX + l] = acc[l];
}

// Kernel 2: per pair p, masked mean of precomp[path_edges[p][l]*L + l] over l < len.
// path_edges / path_len / out are pure streaming (no reuse) -> non-temporal,
// so the 2.6MB precomp table stays resident in each XCD's 4MB L2 and the
// 2.6M random gathers hit L2 instead of bouncing to L3.
__global__ __launch_bounds__(256)
void path_mean_kernel(const int* __restrict__ path_edges,
                      const int* __restrict__ path_len,
                      const float* __restrict__ precomp,
                      float* __restrict__ out, int P) {
    int p = blockIdx.x * blockDim.x + threadIdx.x;
    if (p >= P) return;

    int len = __builtin_nontemporal_load(path_len + p);
    const int* pe = path_edges + (size_t)p * L_MAX;

    // Load all 5 indices unconditionally (always valid in [0,E)), ~coalesced.
    int e0 = __builtin_nontemporal_load(pe + 0);
    int e1 = __builtin_nontemporal_load(pe + 1);
    int e2 = __builtin_nontemporal_load(pe + 2);
    int e3 = __builtin_nontemporal_load(pe + 3);
    int e4 = __builtin_nontemporal_load(pe + 4);

    float s = 0.f;
    if (0 < len) s += precomp[(size_t)e0 * L_MAX + 0];
    if (1 < len) s += precomp[(size_t)e1 * L_MAX + 1];
    if (2 < len) s += precomp[(size_t)e2 * L_MAX + 2];
    if (3 < len) s += precomp[(size_t)e3 * L_MAX + 3];
    if (4 < len) s += precomp[(size_t)e4 * L_MAX + 4];

    // len in [1,5]: rcp approx error ~1ulp, well inside 0.0625 tolerance.
    float r = (len > 0) ? s * __builtin_amdgcn_rcpf((float)len) : 0.f;
    __builtin_nontemporal_store(r, out + p);
}

// Fallback (ws too small): recompute each hop's dot directly from edge_attr.
__global__ __launch_bounds__(256)
void path_mean_direct_kernel(const int* __restrict__ path_edges,
                             const int* __restrict__ path_len,
                             const float* __restrict__ edge_attr,
                             const float* __restrict__ edge_vector,
                             float* __restrict__ out, int P) {
    __shared__ float ev[L_MAX * D_DIM];
    int tid = threadIdx.x;
    if (tid < L_MAX * D_DIM) ev[tid] = edge_vector[tid];
    __syncthreads();

    int p = blockIdx.x * blockDim.x + tid;
    if (p >= P) return;

    int len = path_len[p];
    const int* pe = path_edges + (size_t)p * L_MAX;

    float s = 0.f;
#pragma unroll
    for (int l = 0; l < L_MAX; ++l) {
        if (l < len) {
            const float4* row = (const float4*)(edge_attr + (size_t)pe[l] * D_DIM);
            float d = 0.f;
#pragma unroll
            for (int c4 = 0; c4 < D_DIM / 4; ++c4) {
                float4 a = row[c4];
                const float* evl = ev + l * D_DIM + c4 * 4;
                d += evl[0] * a.x + evl[1] * a.y + evl[2] * a.z + evl[3] * a.w;
            }
            s += d;
        }
    }
    out[p] = (len > 0) ? s / (float)len : 0.f;
}

extern "C" void kernel_launch(void* const* d_in, const int* in_sizes, int n_in,
                              void* d_out, int out_size, void* d_ws, size_t ws_size,
                              hipStream_t stream) {
    // Inputs (setup_inputs order): x [N*D], edge_attr [E*D], edge_vector [L*D],
    // path_edges [P*L] int32, path_len [P] int32. x is UNUSED by the reference.
    const float* edge_attr   = (const float*)d_in[1];
    const float* edge_vector = (const float*)d_in[2];
    const int*   path_edges  = (const int*)d_in[3];
    const int*   path_len    = (const int*)d_in[4];
    float* out = (float*)d_out;

    const int E = in_sizes[1] / D_DIM;
    const int P = in_sizes[4];

    const size_t precomp_bytes = (size_t)E * L_MAX * sizeof(float);

    if (ws_size >= precomp_bytes) {
        float* precomp = (float*)d_ws;
        {
            int block = 256;
            int grid = (E + block - 1) / block;
            precompute_dots_kernel<<<grid, block, 0, stream>>>(edge_attr, edge_vector,
                                                               precomp, E);
        }
        {
            int block = 256;
            int grid = (P + block - 1) / block;
            path_mean_kernel<<<grid, block, 0, stream>>>(path_edges, path_len,
                                                         precomp, out, P);
        }
    } else {
        int block = 256;
        int grid = (P + block - 1) / block;
        path_mean_direct_kernel<<<grid, block, 0, stream>>>(path_edges, path_len,
                                                            edge_attr, edge_vector,
                                                            out, P);
    }
}

// Round 3
// 105.494 us; speedup vs baseline: 4.7269x; 1.0158x over previous
//
#include <hip/hip_runtime.h>

#define L_MAX 5
#define D_DIM 32

typedef float f32x4 __attribute__((ext_vector_type(4)));

// Kernel 1: precomp[e*L + l] = dot(edge_vector[l], edge_attr[e])
// E threads, each reads one 128B row via float4 (non-temporal: pure stream,
// don't pollute L2 — precomp writes SHOULD stay cached for kernel 2).
__global__ __launch_bounds__(256)
void precompute_dots_kernel(const float* __restrict__ edge_attr,
                            const float* __restrict__ edge_vector,
                            float* __restrict__ precomp, int E) {
    __shared__ float ev[L_MAX * D_DIM];
    int tid = threadIdx.x;
    if (tid < L_MAX * D_DIM) ev[tid] = edge_vector[tid];
    __syncthreads();

    int e = blockIdx.x * blockDim.x + tid;
    if (e >= E) return;

    const f32x4* row = (const f32x4*)(edge_attr + (size_t)e * D_DIM);
    float acc[L_MAX];
#pragma unroll
    for (int l = 0; l < L_MAX; ++l) acc[l] = 0.f;

#pragma unroll
    for (int c4 = 0; c4 < D_DIM / 4; ++c4) {
        f32x4 a = __builtin_nontemporal_load(row + c4);
#pragma unroll
        for (int l = 0; l < L_MAX; ++l) {
            const float* evl = ev + l * D_DIM + c4 * 4;
            acc[l] += evl[0] * a.x + evl[1] * a.y + evl[2] * a.z + evl[3] * a.w;
        }
    }
#pragma unroll
    for (int l = 0; l < L_MAX; ++l)
        precomp[(size_t)e * L_MAX + l] = acc[l];
}

// Kernel 2: per pair p, masked mean of precomp[path_edges[p][l]*L + l] over l < len.
// Index loads explicitly vectorized (int4 + int = 2 VMEM instrs/thread);
// gathers are exec-masked so lanes beyond len issue no requests.
__global__ __launch_bounds__(256)
void path_mean_kernel(const int* __restrict__ path_edges,
                      const int* __restrict__ path_len,
                      const float* __restrict__ precomp,
                      float* __restrict__ out, int P) {
    int p = blockIdx.x * blockDim.x + threadIdx.x;
    if (p >= P) return;

    int len = path_len[p];
    const int* pe = path_edges + (size_t)p * L_MAX;

    // 20B per thread: one dwordx4 + one dword (compiler-guaranteed shapes).
    int4 e0123 = *(const int4*)pe;
    int  e4    = pe[4];

    float s = 0.f;
    if (0 < len) s += precomp[(size_t)e0123.x * L_MAX + 0];
    if (1 < len) s += precomp[(size_t)e0123.y * L_MAX + 1];
    if (2 < len) s += precomp[(size_t)e0123.z * L_MAX + 2];
    if (3 < len) s += precomp[(size_t)e0123.w * L_MAX + 3];
    if (4 < len) s += precomp[(size_t)e4      * L_MAX + 4];

    // len in [1,5]: rcp approx error ~1ulp, well inside 0.0625 tolerance.
    float r = (len > 0) ? s * __builtin_amdgcn_rcpf((float)len) : 0.f;
    __builtin_nontemporal_store(r, out + p);
}

// Fallback (ws too small): recompute each hop's dot directly from edge_attr.
__global__ __launch_bounds__(256)
void path_mean_direct_kernel(const int* __restrict__ path_edges,
                             const int* __restrict__ path_len,
                             const float* __restrict__ edge_attr,
                             const float* __restrict__ edge_vector,
                             float* __restrict__ out, int P) {
    __shared__ float ev[L_MAX * D_DIM];
    int tid = threadIdx.x;
    if (tid < L_MAX * D_DIM) ev[tid] = edge_vector[tid];
    __syncthreads();

    int p = blockIdx.x * blockDim.x + tid;
    if (p >= P) return;

    int len = path_len[p];
    const int* pe = path_edges + (size_t)p * L_MAX;

    float s = 0.f;
#pragma unroll
    for (int l = 0; l < L_MAX; ++l) {
        if (l < len) {
            const float4* row = (const float4*)(edge_attr + (size_t)pe[l] * D_DIM);
            float d = 0.f;
#pragma unroll
            for (int c4 = 0; c4 < D_DIM / 4; ++c4) {
                float4 a = row[c4];
                const float* evl = ev + l * D_DIM + c4 * 4;
                d += evl[0] * a.x + evl[1] * a.y + evl[2] * a.z + evl[3] * a.w;
            }
            s += d;
        }
    }
    out[p] = (len > 0) ? s / (float)len : 0.f;
}

extern "C" void kernel_launch(void* const* d_in, const int* in_sizes, int n_in,
                              void* d_out, int out_size, void* d_ws, size_t ws_size,
                              hipStream_t stream) {
    // Inputs (setup_inputs order): x [N*D], edge_attr [E*D], edge_vector [L*D],
    // path_edges [P*L] int32, path_len [P] int32. x is UNUSED by the reference.
    const float* edge_attr   = (const float*)d_in[1];
    const float* edge_vector = (const float*)d_in[2];
    const int*   path_edges  = (const int*)d_in[3];
    const int*   path_len    = (const int*)d_in[4];
    float* out = (float*)d_out;

    const int E = in_sizes[1] / D_DIM;
    const int P = in_sizes[4];

    const size_t precomp_bytes = (size_t)E * L_MAX * sizeof(float);

    if (ws_size >= precomp_bytes) {
        float* precomp = (float*)d_ws;
        {
            int block = 256;
            int grid = (E + block - 1) / block;
            precompute_dots_kernel<<<grid, block, 0, stream>>>(edge_attr, edge_vector,
                                                               precomp, E);
        }
        {
            int block = 256;
            int grid = (P + block - 1) / block;
            path_mean_kernel<<<grid, block, 0, stream>>>(path_edges, path_len,
                                                         precomp, out, P);
        }
    } else {
        int block = 256;
        int grid = (P + block - 1) / block;
        path_mean_direct_kernel<<<grid, block, 0, stream>>>(path_edges, path_len,
                                                            edge_attr, edge_vector,
                                                            out, P);
    }
}

// Round 4
// 101.719 us; speedup vs baseline: 4.9023x; 1.0371x over previous
//
#include <hip/hip_runtime.h>

#define L_MAX 5
#define D_DIM 32

// Kernel 1: precomp[e*L + l] = dot(edge_vector[l], edge_attr[e])
// E threads, each reads one 128B row via float4 and produces 5 scalars.
// Plain cached loads: nt-hints measured as a regression (rounds 2-3).
__global__ __launch_bounds__(256)
void precompute_dots_kernel(const float* __restrict__ edge_attr,
                            const float* __restrict__ edge_vector,
                            float* __restrict__ precomp, int E) {
    __shared__ float ev[L_MAX * D_DIM];
    int tid = threadIdx.x;
    if (tid < L_MAX * D_DIM) ev[tid] = edge_vector[tid];
    __syncthreads();

    int e = blockIdx.x * blockDim.x + tid;
    if (e >= E) return;

    const float4* row = (const float4*)(edge_attr + (size_t)e * D_DIM);
    float acc[L_MAX];
#pragma unroll
    for (int l = 0; l < L_MAX; ++l) acc[l] = 0.f;

#pragma unroll
    for (int c4 = 0; c4 < D_DIM / 4; ++c4) {
        float4 a = row[c4];
#pragma unroll
        for (int l = 0; l < L_MAX; ++l) {
            const float* evl = ev + l * D_DIM + c4 * 4;
            acc[l] += evl[0] * a.x + evl[1] * a.y + evl[2] * a.z + evl[3] * a.w;
        }
    }
#pragma unroll
    for (int l = 0; l < L_MAX; ++l)
        precomp[(size_t)e * L_MAX + l] = acc[l];
}

// Kernel 2: per pair p, masked mean of precomp[path_edges[p][l]*L + l] over l < len.
// Index loads explicitly vectorized (int4 + int = 2 VMEM instrs/thread);
// gathers are exec-masked so lanes beyond len issue no L2 requests.
// Plain cached stream/store: 2.6MB precomp table stays L2-resident regardless.
__global__ __launch_bounds__(256)
void path_mean_kernel(const int* __restrict__ path_edges,
                      const int* __restrict__ path_len,
                      const float* __restrict__ precomp,
                      float* __restrict__ out, int P) {
    int p = blockIdx.x * blockDim.x + threadIdx.x;
    if (p >= P) return;

    int len = path_len[p];
    const int* pe = path_edges + (size_t)p * L_MAX;

    // 20B per thread: one dwordx4 + one dword.
    int4 e0123 = *(const int4*)pe;
    int  e4    = pe[4];

    float s = 0.f;
    if (0 < len) s += precomp[(size_t)e0123.x * L_MAX + 0];
    if (1 < len) s += precomp[(size_t)e0123.y * L_MAX + 1];
    if (2 < len) s += precomp[(size_t)e0123.z * L_MAX + 2];
    if (3 < len) s += precomp[(size_t)e0123.w * L_MAX + 3];
    if (4 < len) s += precomp[(size_t)e4      * L_MAX + 4];

    // len in [1,5]: rcp approx error ~1ulp, well inside tolerance.
    out[p] = (len > 0) ? s * __builtin_amdgcn_rcpf((float)len) : 0.f;
}

// Fallback (ws too small): recompute each hop's dot directly from edge_attr.
__global__ __launch_bounds__(256)
void path_mean_direct_kernel(const int* __restrict__ path_edges,
                             const int* __restrict__ path_len,
                             const float* __restrict__ edge_attr,
                             const float* __restrict__ edge_vector,
                             float* __restrict__ out, int P) {
    __shared__ float ev[L_MAX * D_DIM];
    int tid = threadIdx.x;
    if (tid < L_MAX * D_DIM) ev[tid] = edge_vector[tid];
    __syncthreads();

    int p = blockIdx.x * blockDim.x + tid;
    if (p >= P) return;

    int len = path_len[p];
    const int* pe = path_edges + (size_t)p * L_MAX;

    float s = 0.f;
#pragma unroll
    for (int l = 0; l < L_MAX; ++l) {
        if (l < len) {
            const float4* row = (const float4*)(edge_attr + (size_t)pe[l] * D_DIM);
            float d = 0.f;
#pragma unroll
            for (int c4 = 0; c4 < D_DIM / 4; ++c4) {
                float4 a = row[c4];
                const float* evl = ev + l * D_DIM + c4 * 4;
                d += evl[0] * a.x + evl[1] * a.y + evl[2] * a.z + evl[3] * a.w;
            }
            s += d;
        }
    }
    out[p] = (len > 0) ? s / (float)len : 0.f;
}

extern "C" void kernel_launch(void* const* d_in, const int* in_sizes, int n_in,
                              void* d_out, int out_size, void* d_ws, size_t ws_size,
                              hipStream_t stream) {
    // Inputs (setup_inputs order): x [N*D], edge_attr [E*D], edge_vector [L*D],
    // path_edges [P*L] int32, path_len [P] int32. x is UNUSED by the reference.
    const float* edge_attr   = (const float*)d_in[1];
    const float* edge_vector = (const float*)d_in[2];
    const int*   path_edges  = (const int*)d_in[3];
    const int*   path_len    = (const int*)d_in[4];
    float* out = (float*)d_out;

    const int E = in_sizes[1] / D_DIM;
    const int P = in_sizes[4];

    const size_t precomp_bytes = (size_t)E * L_MAX * sizeof(float);

    if (ws_size >= precomp_bytes) {
        float* precomp = (float*)d_ws;
        {
            int block = 256;
            int grid = (E + block - 1) / block;
            precompute_dots_kernel<<<grid, block, 0, stream>>>(edge_attr, edge_vector,
                                                               precomp, E);
        }
        {
            int block = 256;
            int grid = (P + block - 1) / block;
            path_mean_kernel<<<grid, block, 0, stream>>>(path_edges, path_len,
                                                         precomp, out, P);
        }
    } else {
        int block = 256;
        int grid = (P + block - 1) / block;
        path_mean_direct_kernel<<<grid, block, 0, stream>>>(path_edges, path_len,
                                                            edge_attr, edge_vector,
                                                            out, P);
    }
}